// Round 1
// baseline (992.190 us; speedup 1.0000x reference)
//
#include <hip/hip_runtime.h>

// Problem constants (from setup_inputs): B=16, C=80, sizes 128/64/32.
// d_in order (setup_inputs dict order): heat0, tl0, br0, heat1, tl1, br1, heat2, tl2, br2.

#define NB 4096      // histogram buckets over score in [0,1)
#define CAP 4096     // candidate capacity per (batch, layer)

__device__ __forceinline__ unsigned int ord_f32(float f) {
    unsigned int b = __float_as_uint(f);
    return (b & 0x80000000u) ? ~b : (b | 0x80000000u);
}
__device__ __forceinline__ float unord_f32(unsigned int o) {
    unsigned int b = (o & 0x80000000u) ? (o & 0x7fffffffu) : ~o;
    return __uint_as_float(b);
}
__device__ __forceinline__ int bucket_of(float f) {
    int bi = (int)(f * (float)NB);
    bi = bi < 0 ? 0 : (bi > NB - 1 ? NB - 1 : bi);
    return bi;
}

// ---------------- histogram ----------------
__global__ __launch_bounds__(256) void hist_kernel(
    const float* __restrict__ h0, const float* __restrict__ h1, const float* __restrict__ h2,
    int* __restrict__ hist)
{
    int l = blockIdx.z, b = blockIdx.y, chunk = blockIdx.x;
    int N = (l == 0) ? 1310720 : (l == 1) ? 327680 : 81920;
    if (chunk * 8192 >= N) return;
    const float* heat = (l == 0) ? h0 : (l == 1) ? h1 : h2;
    __shared__ int lh[NB];
    for (int i = threadIdx.x; i < NB; i += 256) lh[i] = 0;
    __syncthreads();
    const float4* p = (const float4*)(heat + (size_t)b * N + (size_t)chunk * 8192);
    for (int i = threadIdx.x; i < 2048; i += 256) {
        float4 v = p[i];
        atomicAdd(&lh[bucket_of(v.x)], 1);
        atomicAdd(&lh[bucket_of(v.y)], 1);
        atomicAdd(&lh[bucket_of(v.z)], 1);
        atomicAdd(&lh[bucket_of(v.w)], 1);
    }
    __syncthreads();
    int* gh = hist + (l * 16 + b) * NB;
    for (int i = threadIdx.x; i < NB; i += 256) {
        int c = lh[i];
        if (c) atomicAdd(&gh[i], c);
    }
}

// ---------------- threshold bucket ----------------
__global__ __launch_bounds__(256) void thresh_kernel(const int* __restrict__ hist,
                                                     int* __restrict__ tb)
{
    int b = blockIdx.x & 15;
    int l = blockIdx.x >> 4;
    int K = (l == 2) ? 1024 : 2000;
    const int* gh = hist + (l * 16 + b) * NB;
    __shared__ int seg[256];
    int s = 0;
    for (int j = 0; j < 16; j++) s += gh[threadIdx.x * 16 + j];
    seg[threadIdx.x] = s;
    __syncthreads();
    if (threadIdx.x == 0) {
        int acc = 0, si;
        for (si = 255; si >= 0; si--) {
            if (acc + seg[si] >= K) break;
            acc += seg[si];
        }
        if (si < 0) si = 0;  // defensive; cannot happen (total >= K)
        int bidx = si * 16 + 15;
        for (; bidx > si * 16; bidx--) {
            acc += gh[bidx];
            if (acc >= K) break;
        }
        tb[l * 16 + b] = bidx;
    }
}

// ---------------- candidate collection ----------------
__global__ __launch_bounds__(256) void collect_kernel(
    const float* __restrict__ h0, const float* __restrict__ h1, const float* __restrict__ h2,
    const int* __restrict__ tb, int* __restrict__ cnt, unsigned long long* __restrict__ cand)
{
    int l = blockIdx.z, b = blockIdx.y, chunk = blockIdx.x;
    int N = (l == 0) ? 1310720 : (l == 1) ? 327680 : 81920;
    if (chunk * 8192 >= N) return;
    const float* heat = (l == 0) ? h0 : (l == 1) ? h1 : h2;
    int t = tb[l * 16 + b];
    int* c = cnt + (l * 16 + b);
    unsigned long long* cd = cand + (size_t)(l * 16 + b) * CAP;
    const float4* p = (const float4*)(heat + (size_t)b * N + (size_t)chunk * 8192);
    int base = chunk * 8192;
    for (int i = threadIdx.x; i < 2048; i += 256) {
        float4 v = p[i];
        float vs[4] = {v.x, v.y, v.z, v.w};
#pragma unroll
        for (int cc = 0; cc < 4; cc++) {
            if (bucket_of(vs[cc]) >= t) {
                int pos = atomicAdd(c, 1);
                if (pos < CAP) {
                    unsigned int idx = (unsigned int)(base + 4 * i + cc);
                    cd[pos] = ((unsigned long long)ord_f32(vs[cc]) << 32) | (unsigned int)(~idx);
                }
            }
        }
    }
}

// ---------------- in-LDS bitonic sort, descending by u64 key ----------------
__device__ void bitonic_desc(unsigned long long* d, int n, int tid, int nt) {
    for (int k = 2; k <= n; k <<= 1) {
        for (int j = k >> 1; j > 0; j >>= 1) {
            __syncthreads();
            for (int i = tid; i < n; i += nt) {
                int ixj = i ^ j;
                if (ixj > i) {
                    unsigned long long a = d[i], bb = d[ixj];
                    bool sw = ((i & k) == 0) ? (a < bb) : (a > bb);
                    if (sw) { d[i] = bb; d[ixj] = a; }
                }
            }
        }
    }
    __syncthreads();
}

// ---------------- per-(b,l): sort candidates, decode, 2nd top-k, build det ----------------
__global__ __launch_bounds__(1024) void select_kernel(
    const float* __restrict__ t0, const float* __restrict__ t1, const float* __restrict__ t2,
    const float* __restrict__ r0, const float* __restrict__ r1, const float* __restrict__ r2,
    const int* __restrict__ cnt, const unsigned long long* __restrict__ cand,
    float* __restrict__ det)
{
    int l = blockIdx.x >> 4;
    int b = blockIdx.x & 15;
    int HW = (l == 0) ? 16384 : (l == 1) ? 4096 : 1024;
    int W  = (l == 0) ? 128 : (l == 1) ? 64 : 32;
    int K  = (l == 2) ? 1024 : 2000;
    float scale = (l == 0) ? 8.f : (l == 1) ? 16.f : 32.f;
    const float* tlp = (l == 0) ? t0 : (l == 1) ? t1 : t2;
    const float* brp = (l == 0) ? r0 : (l == 1) ? r1 : r2;

    __shared__ unsigned long long k1[4096];
    __shared__ unsigned long long k2[2048];
    int tid = threadIdx.x;

    int n = cnt[l * 16 + b];
    if (n > CAP) n = CAP;
    const unsigned long long* cd = cand + (size_t)(l * 16 + b) * CAP;
    for (int i = tid; i < 4096; i += 1024) k1[i] = (i < n) ? cd[i] : 0ull;
    bitonic_desc(k1, 4096, tid, 1024);  // first sync inside covers the load

    // adjusted scores for the first-top-K entries (validity test, exact np rounding)
    for (int k = tid; k < 2048; k += 1024) {
        unsigned long long key = 0ull;
        if (k < K) {
            unsigned long long kk = k1[k];
            unsigned int idx = ~(unsigned int)kk;
            float score = unord_f32((unsigned int)(kk >> 32));
            int sp = (int)(idx % (unsigned)HW);
            float xs = (float)(sp % W), ys = (float)(sp / W);
            float tv0 = tlp[((size_t)b * 2 + 0) * HW + sp];
            float tv1 = tlp[((size_t)b * 2 + 1) * HW + sp];
            float bv0 = brp[((size_t)b * 2 + 0) * HW + sp];
            float bv1 = brp[((size_t)b * 2 + 1) * HW + sp];
            float tlx = __fsub_rn(xs, __fadd_rn(__fmul_rn(1.5f, tv0), 2.25f));
            float tly = __fsub_rn(ys, __fadd_rn(__fmul_rn(1.5f, tv1), 2.25f));
            float brx = __fadd_rn(xs, __fadd_rn(__fmul_rn(1.5f, bv0), 2.25f));
            float bry = __fadd_rn(ys, __fadd_rn(__fmul_rn(1.5f, bv1), 2.25f));
            float s = ((brx < tlx) || (bry < tly)) ? -1.0f : score;
            key = ((unsigned long long)ord_f32(s) << 32) | (unsigned int)(~(unsigned int)k);
        }
        k2[k] = key;
    }
    bitonic_desc(k2, 2048, tid, 1024);

    // write det rows for ranks 0..999
    if (tid < 1000) {
        int r = tid;
        float* drow = det + ((size_t)b * 3000 + (size_t)l * 1000 + r) * 7;
        if (r == 6) {
            float lv = (float)l;
#pragma unroll
            for (int j = 0; j < 7; j++) drow[j] = lv;
        } else {
            unsigned long long key = k2[r];
            int k = (int)(~(unsigned int)key);
            float s = unord_f32((unsigned int)(key >> 32));
            unsigned long long kk = k1[k];
            unsigned int idx = ~(unsigned int)kk;
            int sp = (int)(idx % (unsigned)HW);
            float xs = (float)(sp % W), ys = (float)(sp / W);
            float tv0 = tlp[((size_t)b * 2 + 0) * HW + sp];
            float tv1 = tlp[((size_t)b * 2 + 1) * HW + sp];
            float bv0 = brp[((size_t)b * 2 + 0) * HW + sp];
            float bv1 = brp[((size_t)b * 2 + 1) * HW + sp];
            float tlx = __fsub_rn(xs, __fadd_rn(__fmul_rn(1.5f, tv0), 2.25f));
            float tly = __fsub_rn(ys, __fadd_rn(__fmul_rn(1.5f, tv1), 2.25f));
            float brx = __fadd_rn(xs, __fadd_rn(__fmul_rn(1.5f, bv0), 2.25f));
            float bry = __fadd_rn(ys, __fadd_rn(__fmul_rn(1.5f, bv1), 2.25f));
            drow[0] = s;
            drow[1] = __fmul_rn(tlx, scale);
            drow[2] = __fmul_rn(tly, scale);
            drow[3] = __fmul_rn(brx, scale);
            drow[4] = __fmul_rn(bry, scale);
            drow[5] = 0.f;
            drow[6] = 0.f;
        }
    }
}

// ---------------- final cross-layer top-1000 + gather ----------------
__global__ __launch_bounds__(1024) void final_kernel(const float* __restrict__ det,
                                                     float* __restrict__ out)
{
    int b = blockIdx.x;
    __shared__ unsigned long long k3[4096];
    int tid = threadIdx.x;
    for (int i = tid; i < 4096; i += 1024) {
        unsigned long long key = 0ull;
        if (i < 3000) {
            float s = det[((size_t)b * 3000 + i) * 7];
            key = ((unsigned long long)ord_f32(s) << 32) | (unsigned int)(~(unsigned int)i);
        }
        k3[i] = key;
    }
    bitonic_desc(k3, 4096, tid, 1024);
    if (tid < 1000) {
        int i = (int)(~(unsigned int)k3[tid]);
        const float* src = det + ((size_t)b * 3000 + i) * 7;
        float* dst = out + ((size_t)b * 1000 + tid) * 7;
#pragma unroll
        for (int j = 0; j < 7; j++) dst[j] = src[j];
    }
}

extern "C" void kernel_launch(void* const* d_in, const int* in_sizes, int n_in,
                              void* d_out, int out_size, void* d_ws, size_t ws_size,
                              hipStream_t stream)
{
    (void)in_sizes; (void)n_in; (void)out_size; (void)ws_size;
    const float* h0 = (const float*)d_in[0];
    const float* t0 = (const float*)d_in[1];
    const float* r0 = (const float*)d_in[2];
    const float* h1 = (const float*)d_in[3];
    const float* t1 = (const float*)d_in[4];
    const float* r1 = (const float*)d_in[5];
    const float* h2 = (const float*)d_in[6];
    const float* t2 = (const float*)d_in[7];
    const float* r2 = (const float*)d_in[8];
    float* out = (float*)d_out;

    // Workspace layout (bytes):
    //   hist: 3*16*4096*4 = 786432
    //   cnt : 48*4        = 192      @ 786432
    //   tb  : 48*4        = 192      @ 786624
    //   cand: 3*16*4096*8 = 1572864  @ 786816  (8B aligned)
    //   det : 16*3000*7*4 = 1344000  @ 2359680
    char* ws = (char*)d_ws;
    int* hist = (int*)ws;
    int* cnt  = (int*)(ws + 786432);
    int* tb   = (int*)(ws + 786624);
    unsigned long long* cand = (unsigned long long*)(ws + 786816);
    float* det = (float*)(ws + 2359680);

    // zero hist + cnt (ws is poisoned 0xAA each call)
    hipMemsetAsync(d_ws, 0, 786624, stream);

    dim3 hgrid(160, 16, 3);
    hist_kernel<<<hgrid, 256, 0, stream>>>(h0, h1, h2, hist);
    thresh_kernel<<<48, 256, 0, stream>>>(hist, tb);
    collect_kernel<<<hgrid, 256, 0, stream>>>(h0, h1, h2, tb, cnt, cand);
    select_kernel<<<48, 1024, 0, stream>>>(t0, t1, t2, r0, r1, r2, cnt, cand, det);
    final_kernel<<<16, 1024, 0, stream>>>(det, out);
}

// Round 2
// 377.403 us; speedup vs baseline: 2.6290x; 2.6290x over previous
//
#include <hip/hip_runtime.h>

// B=16, C=80, layer sizes 128/64/32.
// d_in order: heat0, tl0, br0, heat1, tl1, br1, heat2, tl2, br2.

#define NB 1024      // histogram buckets over score in [0,1)
#define CAP 4096     // candidate capacity per (batch, layer)
#define CHUNK_H 32768   // elements per hist block
#define CHUNK_C 16384   // elements per collect block
#define LCAP 1024       // per-block local candidate buffer

__device__ __forceinline__ unsigned int ord_f32(float f) {
    unsigned int b = __float_as_uint(f);
    return (b & 0x80000000u) ? ~b : (b | 0x80000000u);
}
__device__ __forceinline__ float unord_f32(unsigned int o) {
    unsigned int b = (o & 0x80000000u) ? (o & 0x7fffffffu) : ~o;
    return __uint_as_float(b);
}
__device__ __forceinline__ int bucket_of(float f) {
    int bi = (int)(f * (float)NB);
    bi = bi < 0 ? 0 : (bi > NB - 1 ? NB - 1 : bi);
    return bi;
}

__device__ __forceinline__ int layer_N(int l)  { return (l == 0) ? 1310720 : (l == 1) ? 327680 : 81920; }
__device__ __forceinline__ int hist_nchunks(int l) { return (l == 0) ? 40 : (l == 1) ? 10 : 3; }
__device__ __forceinline__ int hist_base(int l)    { return (l == 0) ? 0 : (l == 1) ? 640 : 800; }
// total partials: 40*16 + 10*16 + 3*16 = 848

// ---------------- histogram: per-block LDS hist -> private global partial (no atomics) ----------------
__global__ __launch_bounds__(256) void hist_kernel(
    const float* __restrict__ h0, const float* __restrict__ h1, const float* __restrict__ h2,
    int* __restrict__ ph)
{
    int l = blockIdx.z, b = blockIdx.y, chunk = blockIdx.x;
    int nc = hist_nchunks(l);
    if (chunk >= nc) return;
    int N = layer_N(l);
    int elems = min(CHUNK_H, N - chunk * CHUNK_H);
    const float* heat = (l == 0) ? h0 : (l == 1) ? h1 : h2;
    __shared__ int lh[NB];
    for (int i = threadIdx.x; i < NB; i += 256) lh[i] = 0;
    __syncthreads();
    const float4* p = (const float4*)(heat + (size_t)b * N + (size_t)chunk * CHUNK_H);
    int n4 = elems >> 2;
    for (int i = threadIdx.x; i < n4; i += 256) {
        float4 v = p[i];
        atomicAdd(&lh[bucket_of(v.x)], 1);
        atomicAdd(&lh[bucket_of(v.y)], 1);
        atomicAdd(&lh[bucket_of(v.z)], 1);
        atomicAdd(&lh[bucket_of(v.w)], 1);
    }
    __syncthreads();
    int pidx = hist_base(l) + b * nc + chunk;
    int* dst = ph + (size_t)pidx * NB;
    for (int i = threadIdx.x; i < NB; i += 256) dst[i] = lh[i];
}

// ---------------- threshold bucket: reduce partials, scan from top ----------------
__global__ __launch_bounds__(256) void thresh_kernel(const int* __restrict__ ph,
                                                     int* __restrict__ tb)
{
    int b = blockIdx.x & 15;
    int l = blockIdx.x >> 4;
    int K = (l == 2) ? 1024 : 2000;
    int nc = hist_nchunks(l);
    const int* base = ph + (size_t)(hist_base(l) + b * nc) * NB;
    __shared__ int hh[NB];
    __shared__ int seg[256];
    int s4 = 0;
    for (int j = 0; j < 4; j++) {
        int bkt = threadIdx.x * 4 + j;
        int s = 0;
        for (int c = 0; c < nc; c++) s += base[(size_t)c * NB + bkt];
        hh[bkt] = s;
        s4 += s;
    }
    seg[threadIdx.x] = s4;
    __syncthreads();
    if (threadIdx.x == 0) {
        int acc = 0, si;
        for (si = 255; si >= 0; si--) {
            if (acc + seg[si] >= K) break;
            acc += seg[si];
        }
        if (si < 0) si = 0;  // defensive
        int bidx = si * 4 + 3;
        for (; bidx > si * 4; bidx--) {
            acc += hh[bidx];
            if (acc >= K) break;
        }
        tb[l * 16 + b] = bidx;
    }
}

// ---------------- candidate collection: LDS-aggregated, 1 global atomic per block ----------------
__global__ __launch_bounds__(256) void collect_kernel(
    const float* __restrict__ h0, const float* __restrict__ h1, const float* __restrict__ h2,
    const int* __restrict__ tb, int* __restrict__ cnt, unsigned long long* __restrict__ cand)
{
    int l = blockIdx.z, b = blockIdx.y, chunk = blockIdx.x;
    int N = layer_N(l);
    if (chunk * CHUNK_C >= N) return;
    const float* heat = (l == 0) ? h0 : (l == 1) ? h1 : h2;
    int t = tb[l * 16 + b];

    __shared__ int lcnt;
    __shared__ int gbase;
    __shared__ unsigned long long lbuf[LCAP];
    if (threadIdx.x == 0) lcnt = 0;
    __syncthreads();

    const float4* p = (const float4*)(heat + (size_t)b * N + (size_t)chunk * CHUNK_C);
    int base = chunk * CHUNK_C;
    for (int i = threadIdx.x; i < CHUNK_C / 4; i += 256) {
        float4 v = p[i];
        float vs[4] = {v.x, v.y, v.z, v.w};
#pragma unroll
        for (int cc = 0; cc < 4; cc++) {
            if (bucket_of(vs[cc]) >= t) {
                int pos = atomicAdd(&lcnt, 1);
                if (pos < LCAP) {
                    unsigned int idx = (unsigned int)(base + 4 * i + cc);
                    lbuf[pos] = ((unsigned long long)ord_f32(vs[cc]) << 32) | (unsigned int)(~idx);
                }
            }
        }
    }
    __syncthreads();
    int n = min(lcnt, LCAP);
    if (threadIdx.x == 0) gbase = atomicAdd(cnt + (l * 16 + b), n);
    __syncthreads();
    unsigned long long* cd = cand + (size_t)(l * 16 + b) * CAP;
    int g0 = gbase;
    for (int i = threadIdx.x; i < n; i += 256) {
        int pos = g0 + i;
        if (pos < CAP) cd[pos] = lbuf[i];
    }
}

// ---------------- in-LDS bitonic sort, descending by u64 key ----------------
__device__ void bitonic_desc(unsigned long long* d, int n, int tid, int nt) {
    for (int k = 2; k <= n; k <<= 1) {
        for (int j = k >> 1; j > 0; j >>= 1) {
            __syncthreads();
            for (int i = tid; i < n; i += nt) {
                int ixj = i ^ j;
                if (ixj > i) {
                    unsigned long long a = d[i], bb = d[ixj];
                    bool sw = ((i & k) == 0) ? (a < bb) : (a > bb);
                    if (sw) { d[i] = bb; d[ixj] = a; }
                }
            }
        }
    }
    __syncthreads();
}

// ---------------- per-(b,l): sort candidates, decode, 2nd top-k, build det ----------------
__global__ __launch_bounds__(1024) void select_kernel(
    const float* __restrict__ t0, const float* __restrict__ t1, const float* __restrict__ t2,
    const float* __restrict__ r0, const float* __restrict__ r1, const float* __restrict__ r2,
    const int* __restrict__ cnt, const unsigned long long* __restrict__ cand,
    float* __restrict__ det)
{
    int l = blockIdx.x >> 4;
    int b = blockIdx.x & 15;
    int HW = (l == 0) ? 16384 : (l == 1) ? 4096 : 1024;
    int W  = (l == 0) ? 128 : (l == 1) ? 64 : 32;
    int K  = (l == 2) ? 1024 : 2000;
    float scale = (l == 0) ? 8.f : (l == 1) ? 16.f : 32.f;
    const float* tlp = (l == 0) ? t0 : (l == 1) ? t1 : t2;
    const float* brp = (l == 0) ? r0 : (l == 1) ? r1 : r2;

    __shared__ unsigned long long k1[4096];
    __shared__ unsigned long long k2[2048];
    int tid = threadIdx.x;

    int n = cnt[l * 16 + b];
    if (n > CAP) n = CAP;
    const unsigned long long* cd = cand + (size_t)(l * 16 + b) * CAP;
    for (int i = tid; i < 4096; i += 1024) k1[i] = (i < n) ? cd[i] : 0ull;
    bitonic_desc(k1, 4096, tid, 1024);  // first sync inside covers the load

    for (int k = tid; k < 2048; k += 1024) {
        unsigned long long key = 0ull;
        if (k < K) {
            unsigned long long kk = k1[k];
            unsigned int idx = ~(unsigned int)kk;
            float score = unord_f32((unsigned int)(kk >> 32));
            int sp = (int)(idx % (unsigned)HW);
            float xs = (float)(sp % W), ys = (float)(sp / W);
            float tv0 = tlp[((size_t)b * 2 + 0) * HW + sp];
            float tv1 = tlp[((size_t)b * 2 + 1) * HW + sp];
            float bv0 = brp[((size_t)b * 2 + 0) * HW + sp];
            float bv1 = brp[((size_t)b * 2 + 1) * HW + sp];
            float tlx = __fsub_rn(xs, __fadd_rn(__fmul_rn(1.5f, tv0), 2.25f));
            float tly = __fsub_rn(ys, __fadd_rn(__fmul_rn(1.5f, tv1), 2.25f));
            float brx = __fadd_rn(xs, __fadd_rn(__fmul_rn(1.5f, bv0), 2.25f));
            float bry = __fadd_rn(ys, __fadd_rn(__fmul_rn(1.5f, bv1), 2.25f));
            float s = ((brx < tlx) || (bry < tly)) ? -1.0f : score;
            key = ((unsigned long long)ord_f32(s) << 32) | (unsigned int)(~(unsigned int)k);
        }
        k2[k] = key;
    }
    bitonic_desc(k2, 2048, tid, 1024);

    if (tid < 1000) {
        int r = tid;
        float* drow = det + ((size_t)b * 3000 + (size_t)l * 1000 + r) * 7;
        if (r == 6) {
            float lv = (float)l;
#pragma unroll
            for (int j = 0; j < 7; j++) drow[j] = lv;
        } else {
            unsigned long long key = k2[r];
            int k = (int)(~(unsigned int)key);
            float s = unord_f32((unsigned int)(key >> 32));
            unsigned long long kk = k1[k];
            unsigned int idx = ~(unsigned int)kk;
            int sp = (int)(idx % (unsigned)HW);
            float xs = (float)(sp % W), ys = (float)(sp / W);
            float tv0 = tlp[((size_t)b * 2 + 0) * HW + sp];
            float tv1 = tlp[((size_t)b * 2 + 1) * HW + sp];
            float bv0 = brp[((size_t)b * 2 + 0) * HW + sp];
            float bv1 = brp[((size_t)b * 2 + 1) * HW + sp];
            float tlx = __fsub_rn(xs, __fadd_rn(__fmul_rn(1.5f, tv0), 2.25f));
            float tly = __fsub_rn(ys, __fadd_rn(__fmul_rn(1.5f, tv1), 2.25f));
            float brx = __fadd_rn(xs, __fadd_rn(__fmul_rn(1.5f, bv0), 2.25f));
            float bry = __fadd_rn(ys, __fadd_rn(__fmul_rn(1.5f, bv1), 2.25f));
            drow[0] = s;
            drow[1] = __fmul_rn(tlx, scale);
            drow[2] = __fmul_rn(tly, scale);
            drow[3] = __fmul_rn(brx, scale);
            drow[4] = __fmul_rn(bry, scale);
            drow[5] = 0.f;
            drow[6] = 0.f;
        }
    }
}

// ---------------- final cross-layer top-1000 + gather ----------------
__global__ __launch_bounds__(1024) void final_kernel(const float* __restrict__ det,
                                                     float* __restrict__ out)
{
    int b = blockIdx.x;
    __shared__ unsigned long long k3[4096];
    int tid = threadIdx.x;
    for (int i = tid; i < 4096; i += 1024) {
        unsigned long long key = 0ull;
        if (i < 3000) {
            float s = det[((size_t)b * 3000 + i) * 7];
            key = ((unsigned long long)ord_f32(s) << 32) | (unsigned int)(~(unsigned int)i);
        }
        k3[i] = key;
    }
    bitonic_desc(k3, 4096, tid, 1024);
    if (tid < 1000) {
        int i = (int)(~(unsigned int)k3[tid]);
        const float* src = det + ((size_t)b * 3000 + i) * 7;
        float* dst = out + ((size_t)b * 1000 + tid) * 7;
#pragma unroll
        for (int j = 0; j < 7; j++) dst[j] = src[j];
    }
}

extern "C" void kernel_launch(void* const* d_in, const int* in_sizes, int n_in,
                              void* d_out, int out_size, void* d_ws, size_t ws_size,
                              hipStream_t stream)
{
    (void)in_sizes; (void)n_in; (void)out_size; (void)ws_size;
    const float* h0 = (const float*)d_in[0];
    const float* t0 = (const float*)d_in[1];
    const float* r0 = (const float*)d_in[2];
    const float* h1 = (const float*)d_in[3];
    const float* t1 = (const float*)d_in[4];
    const float* r1 = (const float*)d_in[5];
    const float* h2 = (const float*)d_in[6];
    const float* t2 = (const float*)d_in[7];
    const float* r2 = (const float*)d_in[8];
    float* out = (float*)d_out;

    // Workspace layout (bytes):
    //   ph  : 848*1024*4 = 3473408   @ 0        (partial hists, no init needed)
    //   cnt : 48*4       = 192       @ 3473408  (memset 0)
    //   tb  : 48*4       = 192       @ 3473600
    //   cand: 48*4096*8  = 1572864   @ 3473792  (8B aligned)
    //   det : 16*3000*7*4= 1344000   @ 5046656
    char* ws = (char*)d_ws;
    int* ph   = (int*)ws;
    int* cnt  = (int*)(ws + 3473408);
    int* tb   = (int*)(ws + 3473600);
    unsigned long long* cand = (unsigned long long*)(ws + 3473792);
    float* det = (float*)(ws + 5046656);

    hipMemsetAsync(cnt, 0, 192, stream);

    hist_kernel<<<dim3(40, 16, 3), 256, 0, stream>>>(h0, h1, h2, ph);
    thresh_kernel<<<48, 256, 0, stream>>>(ph, tb);
    collect_kernel<<<dim3(80, 16, 3), 256, 0, stream>>>(h0, h1, h2, tb, cnt, cand);
    select_kernel<<<48, 1024, 0, stream>>>(t0, t1, t2, r0, r1, r2, cnt, cand, det);
    final_kernel<<<16, 1024, 0, stream>>>(det, out);
}

// Round 3
// 273.874 us; speedup vs baseline: 3.6228x; 1.3780x over previous
//
#include <hip/hip_runtime.h>

// B=16, C=80, layer sizes 128/64/32.
// d_in order: heat0, tl0, br0, heat1, tl1, br1, heat2, tl2, br2.

#define NB 1024      // histogram buckets over score in [0,1)
#define CAP2 2048    // capacity per candidate sub-list (hi / boundary)
#define CHUNK_H 32768   // elements per hist block
#define CHUNK_C 16384   // elements per collect block
#define LCAP 1024       // per-block local candidate buffer (per list)

__device__ __forceinline__ unsigned int ord_f32(float f) {
    unsigned int b = __float_as_uint(f);
    return (b & 0x80000000u) ? ~b : (b | 0x80000000u);
}
__device__ __forceinline__ float unord_f32(unsigned int o) {
    unsigned int b = (o & 0x80000000u) ? (o & 0x7fffffffu) : ~o;
    return __uint_as_float(b);
}
__device__ __forceinline__ int bucket_of(float f) {
    int bi = (int)(f * (float)NB);
    bi = bi < 0 ? 0 : (bi > NB - 1 ? NB - 1 : bi);
    return bi;
}

__device__ __forceinline__ int layer_N(int l)  { return (l == 0) ? 1310720 : (l == 1) ? 327680 : 81920; }
__device__ __forceinline__ int hist_nchunks(int l) { return (l == 0) ? 40 : (l == 1) ? 10 : 3; }
__device__ __forceinline__ int hist_base(int l)    { return (l == 0) ? 0 : (l == 1) ? 640 : 800; }
// total partials: 40*16 + 10*16 + 3*16 = 848

// ---------------- histogram: per-block LDS hist -> private global partial ----------------
__global__ __launch_bounds__(256) void hist_kernel(
    const float* __restrict__ h0, const float* __restrict__ h1, const float* __restrict__ h2,
    int* __restrict__ ph)
{
    int l = blockIdx.z, b = blockIdx.y, chunk = blockIdx.x;
    int nc = hist_nchunks(l);
    if (chunk >= nc) return;
    int N = layer_N(l);
    int elems = min(CHUNK_H, N - chunk * CHUNK_H);
    const float* heat = (l == 0) ? h0 : (l == 1) ? h1 : h2;
    __shared__ int lh[NB];
    for (int i = threadIdx.x; i < NB; i += 256) lh[i] = 0;
    __syncthreads();
    const float4* p = (const float4*)(heat + (size_t)b * N + (size_t)chunk * CHUNK_H);
    int n4 = elems >> 2;
    for (int i = threadIdx.x; i < n4; i += 256) {
        float4 v = p[i];
        atomicAdd(&lh[bucket_of(v.x)], 1);
        atomicAdd(&lh[bucket_of(v.y)], 1);
        atomicAdd(&lh[bucket_of(v.z)], 1);
        atomicAdd(&lh[bucket_of(v.w)], 1);
    }
    __syncthreads();
    int pidx = hist_base(l) + b * nc + chunk;
    int* dst = ph + (size_t)pidx * NB;
    for (int i = threadIdx.x; i < NB; i += 256) dst[i] = lh[i];
}

// ---------------- threshold bucket ----------------
__global__ __launch_bounds__(256) void thresh_kernel(const int* __restrict__ ph,
                                                     int* __restrict__ tb)
{
    int b = blockIdx.x & 15;
    int l = blockIdx.x >> 4;
    int K = (l == 2) ? 1024 : 2000;
    int nc = hist_nchunks(l);
    const int* base = ph + (size_t)(hist_base(l) + b * nc) * NB;
    __shared__ int hh[NB];
    __shared__ int seg[256];
    int s4 = 0;
    for (int j = 0; j < 4; j++) {
        int bkt = threadIdx.x * 4 + j;
        int s = 0;
        for (int c = 0; c < nc; c++) s += base[(size_t)c * NB + bkt];
        hh[bkt] = s;
        s4 += s;
    }
    seg[threadIdx.x] = s4;
    __syncthreads();
    if (threadIdx.x == 0) {
        int acc = 0, si;
        for (si = 255; si >= 0; si--) {
            if (acc + seg[si] >= K) break;
            acc += seg[si];
        }
        if (si < 0) si = 0;  // defensive
        int bidx = si * 4 + 3;
        for (; bidx > si * 4; bidx--) {
            acc += hh[bidx];
            if (acc >= K) break;
        }
        tb[l * 16 + b] = bidx;
    }
}

// ---------------- collection into TWO lists: hi (bucket>t) and boundary (bucket==t) ----------------
__global__ __launch_bounds__(256) void collect_kernel(
    const float* __restrict__ h0, const float* __restrict__ h1, const float* __restrict__ h2,
    const int* __restrict__ tb, int* __restrict__ cnt, unsigned long long* __restrict__ cand)
{
    int l = blockIdx.z, b = blockIdx.y, chunk = blockIdx.x;
    int N = layer_N(l);
    if (chunk * CHUNK_C >= N) return;
    const float* heat = (l == 0) ? h0 : (l == 1) ? h1 : h2;
    int t = tb[l * 16 + b];
    int bl = l * 16 + b;

    __shared__ int lc[2];
    __shared__ int gb[2];
    __shared__ unsigned long long lbuf[2][LCAP];
    if (threadIdx.x < 2) lc[threadIdx.x] = 0;
    __syncthreads();

    const float4* p = (const float4*)(heat + (size_t)b * N + (size_t)chunk * CHUNK_C);
    int base = chunk * CHUNK_C;
    for (int i = threadIdx.x; i < CHUNK_C / 4; i += 256) {
        float4 v = p[i];
        float vs[4] = {v.x, v.y, v.z, v.w};
#pragma unroll
        for (int cc = 0; cc < 4; cc++) {
            int bk = bucket_of(vs[cc]);
            if (bk >= t) {
                int which = (bk > t) ? 0 : 1;
                int pos = atomicAdd(&lc[which], 1);
                if (pos < LCAP) {
                    unsigned int idx = (unsigned int)(base + 4 * i + cc);
                    lbuf[which][pos] = ((unsigned long long)ord_f32(vs[cc]) << 32) | (unsigned int)(~idx);
                }
            }
        }
    }
    __syncthreads();
    if (threadIdx.x < 2) {
        int n = min(lc[threadIdx.x], LCAP);
        gb[threadIdx.x] = atomicAdd(cnt + bl * 2 + threadIdx.x, n);
    }
    __syncthreads();
#pragma unroll
    for (int w = 0; w < 2; w++) {
        int n = min(lc[w], LCAP);
        unsigned long long* cd = cand + ((size_t)bl * 2 + w) * CAP2;
        int g0 = gb[w];
        for (int i = threadIdx.x; i < n; i += 256) {
            int pos = g0 + i;
            if (pos < CAP2) cd[pos] = lbuf[w][i];
        }
    }
}

// ---------------- in-LDS bitonic sort, descending by u64 key ----------------
__device__ void bitonic_desc(unsigned long long* d, int n, int tid, int nt) {
    for (int k = 2; k <= n; k <<= 1) {
        for (int j = k >> 1; j > 0; j >>= 1) {
            __syncthreads();
            for (int i = tid; i < n; i += nt) {
                int ixj = i ^ j;
                if (ixj > i) {
                    unsigned long long a = d[i], bb = d[ixj];
                    bool sw = ((i & k) == 0) ? (a < bb) : (a > bb);
                    if (sw) { d[i] = bb; d[ixj] = a; }
                }
            }
        }
    }
    __syncthreads();
}

// ---------------- sort one 2048-list per block (96 blocks), in-place in global ----------------
__global__ __launch_bounds__(1024) void sort_kernel(const int* __restrict__ cnt,
                                                    unsigned long long* __restrict__ cand)
{
    int idx = blockIdx.x;          // bl*2 + which
    int n = min(cnt[idx], CAP2);
    unsigned long long* src = cand + (size_t)idx * CAP2;
    __shared__ unsigned long long sd[CAP2];
    int tid = threadIdx.x;
    for (int i = tid; i < CAP2; i += 1024) sd[i] = (i < n) ? src[i] : 0ull;
    bitonic_desc(sd, CAP2, tid, 1024);   // first barrier inside covers load
    for (int i = tid; i < CAP2; i += 1024) src[i] = sd[i];
}

// ---------------- build det: concat(hi,bd), validity, stable partition, write rows ----------------
__global__ __launch_bounds__(1024) void build_kernel(
    const float* __restrict__ t0, const float* __restrict__ t1, const float* __restrict__ t2,
    const float* __restrict__ r0, const float* __restrict__ r1, const float* __restrict__ r2,
    const int* __restrict__ cnt, const unsigned long long* __restrict__ cand,
    float* __restrict__ det)
{
    int l = blockIdx.x >> 4;
    int b = blockIdx.x & 15;
    int bl = l * 16 + b;
    int HW = (l == 0) ? 16384 : (l == 1) ? 4096 : 1024;
    int W  = (l == 0) ? 128 : (l == 1) ? 64 : 32;
    int K  = (l == 2) ? 1024 : 2000;
    float scale = (l == 0) ? 8.f : (l == 1) ? 16.f : 32.f;
    const float* tlp = (l == 0) ? t0 : (l == 1) ? t1 : t2;
    const float* brp = (l == 0) ? r0 : (l == 1) ? r1 : r2;

    int n_hi = min(cnt[bl * 2], CAP2);
    const unsigned long long* hi = cand + (size_t)(bl * 2) * CAP2;
    const unsigned long long* bd = cand + (size_t)(bl * 2 + 1) * CAP2;

    __shared__ int scan[1024];
    int tid = threadIdx.x;

    // each thread handles k = 2*tid, 2*tid+1 (consecutive -> correct scan order)
    float s_[2], bx_[2][4];
    int f_[2];
#pragma unroll
    for (int q = 0; q < 2; q++) {
        int k = 2 * tid + q;
        f_[q] = 0;
        if (k < K) {
            unsigned long long kk = (k < n_hi) ? hi[k] : bd[k - n_hi];
            unsigned int idx = ~(unsigned int)kk;
            float score = unord_f32((unsigned int)(kk >> 32));
            int sp = (int)(idx % (unsigned)HW);
            float xs = (float)(sp % W), ys = (float)(sp / W);
            float tv0 = tlp[((size_t)b * 2 + 0) * HW + sp];
            float tv1 = tlp[((size_t)b * 2 + 1) * HW + sp];
            float bv0 = brp[((size_t)b * 2 + 0) * HW + sp];
            float bv1 = brp[((size_t)b * 2 + 1) * HW + sp];
            float tlx = __fsub_rn(xs, __fadd_rn(__fmul_rn(1.5f, tv0), 2.25f));
            float tly = __fsub_rn(ys, __fadd_rn(__fmul_rn(1.5f, tv1), 2.25f));
            float brx = __fadd_rn(xs, __fadd_rn(__fmul_rn(1.5f, bv0), 2.25f));
            float bry = __fadd_rn(ys, __fadd_rn(__fmul_rn(1.5f, bv1), 2.25f));
            bool invalid = (brx < tlx) || (bry < tly);
            f_[q] = invalid ? 0 : 1;
            s_[q] = invalid ? -1.0f : score;
            bx_[q][0] = __fmul_rn(tlx, scale);
            bx_[q][1] = __fmul_rn(tly, scale);
            bx_[q][2] = __fmul_rn(brx, scale);
            bx_[q][3] = __fmul_rn(bry, scale);
        }
    }
    int mysum = f_[0] + f_[1];
    scan[tid] = mysum;
    __syncthreads();
    // Hillis-Steele inclusive scan over 1024 entries
    for (int off = 1; off < 1024; off <<= 1) {
        int v = (tid >= off) ? scan[tid - off] : 0;
        __syncthreads();
        scan[tid] += v;
        __syncthreads();
    }
    int V = scan[1023];
    int base_excl = scan[tid] - mysum;

    float* dbase = det + ((size_t)b * 3000 + (size_t)l * 1000) * 7;
#pragma unroll
    for (int q = 0; q < 2; q++) {
        int k = 2 * tid + q;
        if (k < K) {
            int pos = base_excl + (q == 1 ? f_[0] : 0);   // # valid before k
            int rank = f_[q] ? pos : V + (k - pos);
            if (rank < 1000 && rank != 6) {
                float* drow = dbase + (size_t)rank * 7;
                drow[0] = s_[q];
                drow[1] = bx_[q][0];
                drow[2] = bx_[q][1];
                drow[3] = bx_[q][2];
                drow[4] = bx_[q][3];
                drow[5] = 0.f;
                drow[6] = 0.f;
            }
        }
    }
    if (tid == 0) {
        float lv = (float)l;
        float* drow = dbase + 6 * 7;
#pragma unroll
        for (int j = 0; j < 7; j++) drow[j] = lv;
    }
}

// ---------------- final: merge-rank of 3 sorted lists (+3 clobbered singletons) ----------------
__device__ __forceinline__ bool key_gt(float sa, int ga, float sb, int gb) {
    return (sa > sb) || (sa == sb && ga < gb);
}

__global__ __launch_bounds__(1024) void final_kernel(const float* __restrict__ det,
                                                     float* __restrict__ out)
{
    int b = blockIdx.x;
    __shared__ float sc[3000];
    int tid = threadIdx.x;
    const float* dbase = det + (size_t)b * 3000 * 7;
    for (int i = tid; i < 3000; i += 1024) sc[i] = dbase[(size_t)i * 7];
    __syncthreads();

    for (int e = tid; e < 3000; e += 1024) {
        float se = sc[e];
        int ge = e;
        int rank = 0;
        // three 999-lists (each layer minus its position-6 row)
#pragma unroll
        for (int lp = 0; lp < 3; lp++) {
            int lo = 0, hiB = 999;
            while (lo < hiB) {
                int mid = (lo + hiB) >> 1;
                int p = mid + (mid >= 6 ? 1 : 0);
                int g = lp * 1000 + p;
                if (key_gt(sc[g], g, se, ge)) lo = mid + 1; else hiB = mid;
            }
            rank += lo;
        }
        // three singletons (row 6 of each layer, value = layer)
#pragma unroll
        for (int ls = 0; ls < 3; ls++) {
            int g = ls * 1000 + 6;
            if (g != e && key_gt((float)ls, g, se, ge)) rank++;
        }
        if (rank < 1000) {
            const float* src = dbase + (size_t)e * 7;
            float* dst = out + ((size_t)b * 1000 + rank) * 7;
#pragma unroll
            for (int j = 0; j < 7; j++) dst[j] = src[j];
        }
    }
}

extern "C" void kernel_launch(void* const* d_in, const int* in_sizes, int n_in,
                              void* d_out, int out_size, void* d_ws, size_t ws_size,
                              hipStream_t stream)
{
    (void)in_sizes; (void)n_in; (void)out_size; (void)ws_size;
    const float* h0 = (const float*)d_in[0];
    const float* t0 = (const float*)d_in[1];
    const float* r0 = (const float*)d_in[2];
    const float* h1 = (const float*)d_in[3];
    const float* t1 = (const float*)d_in[4];
    const float* r1 = (const float*)d_in[5];
    const float* h2 = (const float*)d_in[6];
    const float* t2 = (const float*)d_in[7];
    const float* r2 = (const float*)d_in[8];
    float* out = (float*)d_out;

    // Workspace layout (bytes):
    //   ph  : 848*1024*4 = 3473408   @ 0
    //   cnt : 96*4       = 384       @ 3473408  (memset 0)
    //   tb  : 48*4       = 192       @ 3473792
    //   cand: 96*2048*8  = 1572864   @ 3473984  (8B aligned)
    //   det : 16*3000*7*4= 1344000   @ 5046848
    char* ws = (char*)d_ws;
    int* ph   = (int*)ws;
    int* cnt  = (int*)(ws + 3473408);
    int* tb   = (int*)(ws + 3473792);
    unsigned long long* cand = (unsigned long long*)(ws + 3473984);
    float* det = (float*)(ws + 5046848);

    hipMemsetAsync(cnt, 0, 384, stream);

    hist_kernel<<<dim3(40, 16, 3), 256, 0, stream>>>(h0, h1, h2, ph);
    thresh_kernel<<<48, 256, 0, stream>>>(ph, tb);
    collect_kernel<<<dim3(80, 16, 3), 256, 0, stream>>>(h0, h1, h2, tb, cnt, cand);
    sort_kernel<<<96, 1024, 0, stream>>>(cnt, cand);
    build_kernel<<<48, 1024, 0, stream>>>(t0, t1, t2, r0, r1, r2, cnt, cand, det);
    final_kernel<<<16, 1024, 0, stream>>>(det, out);
}